// Round 1
// 463.094 us; speedup vs baseline: 1.0447x; 1.0447x over previous
//
#include <hip/hip_runtime.h>

// 3-layer LSTM (B=8192, T=336, F=8, H=20) + FC(20->20 relu) + FC(20->1).
//
// Round 9 (on top of R8 wave-specialized pipeline):
//  a) BARRIER FIX: __syncthreads() drains vmcnt(0) -> wave0's cold-HBM x
//     prefetch (~900cy) landed on every step's critical path for ALL waves.
//     Replaced with raw `s_waitcnt lgkmcnt(0); s_barrier` (LDS ordering is
//     all the cross-wave handoff needs; x loads are wave0-private).
//  b) X PREFETCH DEPTH 2: dwordx4 loads carry 2 timesteps (lane q holds
//     floats 4q..4q+3 of a 16-float pair). One load per 2 iters, consumed
//     2 iterations after issue -> ~2 iters of slack > HBM latency.
//  c) LDS XOR-SWIZZLE: zT1/zT2 rows are 128B -> ds_read_b128 at
//     src[n*64+q*8] was a 16-way bank conflict (SQ_LDS_BANK_CONFLICT=8.5e7,
//     ~36% of cycles). col ^= (n&7)<<3 (64-f16 rows) / (n&3)<<3 (zT0)
//     spreads the 16 n-lanes across 8 slots -> 2-way (free). Same XOR on
//     reads and writes; all accesses <=8B-aligned so no slot straddle.
//
// MFMA layouts (m89/m120-verified): A[m][k]: m=lane&15,k=(lane>>4)*8+j;
// B[k][n]: n=lane&15,k=(lane>>4)*8+j; D[m][n]: n=lane&15,m=(lane>>4)*4+reg.

#define T_LEN 336

typedef _Float16 f16;
typedef _Float16 f16x2 __attribute__((ext_vector_type(2)));
typedef _Float16 f16x4 __attribute__((ext_vector_type(4)));
typedef _Float16 f16x8 __attribute__((ext_vector_type(8)));
typedef float f32x4 __attribute__((ext_vector_type(4)));

#define MFMA(a, b, c) __builtin_amdgcn_mfma_f32_16x16x32_f16((a), (b), (c), 0, 0, 0)

// row-swizzle for bank-conflict-free LDS (16B-slot XOR, bijective per row)
#define SWZ1(n, c) ((c) ^ (((n) & 7) << 3))   // 64-f16 (128B) rows: zT1/zT2
#define SWZ0(n, c) ((c) ^ (((n) & 3) << 3))   // 32-f16 (64B)  rows: zT0

__device__ __forceinline__ float sigm(float x) {
  return __builtin_amdgcn_rcpf(1.0f + __builtin_amdgcn_exp2f(-1.4426950408889634f * x));
}
__device__ __forceinline__ float tanh_fast(float x) {
  return 2.0f * __builtin_amdgcn_rcpf(1.0f + __builtin_amdgcn_exp2f(-2.8853900817779268f * x)) - 1.0f;
}

// gate-aligned tiles: lane(q,n) reg r = unit 4q+r, elem n — i,f,g,o in-lane
#define CELLS4(DI, DF, DG, DO, HV) {                                                        \
  { float i_=sigm((DI)[0]), f_=sigm((DF)[0]), g_=tanh_fast((DG)[0]), o_=sigm((DO)[0]);      \
    c0 = f_*c0 + i_*g_; (HV)[0] = (f16)(o_*tanh_fast(c0)); }                                \
  { float i_=sigm((DI)[1]), f_=sigm((DF)[1]), g_=tanh_fast((DG)[1]), o_=sigm((DO)[1]);      \
    c1 = f_*c1 + i_*g_; (HV)[1] = (f16)(o_*tanh_fast(c1)); }                                \
  { float i_=sigm((DI)[2]), f_=sigm((DF)[2]), g_=tanh_fast((DG)[2]), o_=sigm((DO)[2]);      \
    c2 = f_*c2 + i_*g_; (HV)[2] = (f16)(o_*tanh_fast(c2)); }                                \
  { float i_=sigm((DI)[3]), f_=sigm((DF)[3]), g_=tanh_fast((DG)[3]), o_=sigm((DO)[3]);      \
    c3 = f_*c3 + i_*g_; (HV)[3] = (f16)(o_*tanh_fast(c3)); } }

// leftover tile (units 16..19 packed 4 rows/gate): bounce through GB (wave-private)
#define CELL_L(DL, HOUT, GB) {                                                              \
  *(f32x4*)&GB[(q * 16 + n) * 4] = (DL);                                                    \
  float i_ = sigm(GB[n * 4 + q]);                                                           \
  float f_ = sigm(GB[(16 + n) * 4 + q]);                                                    \
  float g_ = tanh_fast(GB[(32 + n) * 4 + q]);                                               \
  float o_ = sigm(GB[(48 + n) * 4 + q]);                                                    \
  cL = f_*cL + i_*g_; HOUT = (f16)(o_*tanh_fast(cL)); }

__global__ __launch_bounds__(192, 2) void lstm3_ws_kernel(
    const float* __restrict__ x,
    const float* __restrict__ Wih0, const float* __restrict__ Whh0,
    const float* __restrict__ bih0, const float* __restrict__ bhh0,
    const float* __restrict__ Wih1, const float* __restrict__ Whh1,
    const float* __restrict__ bih1, const float* __restrict__ bhh1,
    const float* __restrict__ Wih2, const float* __restrict__ Whh2,
    const float* __restrict__ bih2, const float* __restrict__ bhh2,
    const float* __restrict__ fc1w, const float* __restrict__ fc1b,
    const float* __restrict__ fc2w, const float* __restrict__ fc2b,
    float* __restrict__ out)
{
  __shared__ __align__(16) f16 zT0[16 * 32];        // wave0-private: x8|h0 20|pad4 (swizzled)
  __shared__ __align__(16) f16 zT1[2][16 * 64];     // parity: h0 20|h1 20|pad24  (swizzled)
  __shared__ __align__(16) f16 zT2[2][16 * 64];     // parity: h1 20|h2 20|pad24  (swizzled)
  __shared__ __align__(16) float gbuf[3][256];      // per-wave leftover bounce
  __shared__ __align__(16) float pbuf[64];          // fc2 partials

  const int tid  = threadIdx.x;
  const int w    = tid >> 6;        // wave id = layer id
  const int lane = tid & 63;
  const int n = lane & 15;          // elem (M/N index)
  const int q = lane >> 4;          // quad

  // ---- zero z buffers (h(.)=0 initial, pads 0; swizzle irrelevant for 0) ----
  {
    f16x8 zer;
#pragma unroll
    for (int j = 0; j < 8; ++j) zer[j] = (f16)0.f;
    for (int i = tid; i < 64; i += 192)  ((f16x8*)zT0)[i] = zer;
    for (int i = tid; i < 256; i += 192) ((f16x8*)&zT1[0][0])[i] = zer;
    for (int i = tid; i < 256; i += 192) ((f16x8*)&zT2[0][0])[i] = zer;
  }
  __syncthreads();

  // ---- per-wave register-resident fragments ----
  auto rowmap = [](int T, int m) { return T < 4 ? T * 20 + m : (m >> 2) * 20 + 16 + (m & 3); };

  f16x8 Fa0{}, Fa1{}, Fa2{}, Fa3{}, Fa4{};   // chunk 0 (or full K=32 for L0)
  f16x8 Fb0{}, Fb1{}, Fb2{}, Fb3{}, Fb4{};   // chunk 1 (unused by wave0)
  f32x4 Bi{}, Bf{}, Bg{}, Bo{}, BL{};
  float c0 = 0.f, c1 = 0.f, c2 = 0.f, c3 = 0.f, cL = 0.f;

  if (w == 0) {
    auto gA0 = [&](int T) {
      int row = rowmap(T, n);
      f16x8 r;
#pragma unroll
      for (int j = 0; j < 8; ++j) {
        int k = q * 8 + j;
        float v = (k < 8) ? Wih0[row * 8 + k] : (k < 28 ? Whh0[row * 20 + k - 8] : 0.f);
        r[j] = (f16)v;
      }
      return r;
    };
    Fa0 = gA0(0); Fa1 = gA0(1); Fa2 = gA0(2); Fa3 = gA0(3); Fa4 = gA0(4);
    auto gB = [&](int T) {
      f32x4 r;
#pragma unroll
      for (int j = 0; j < 4; ++j) { int row = rowmap(T, q * 4 + j); r[j] = bih0[row] + bhh0[row]; }
      return r;
    };
    Bi = gB(0); Bf = gB(1); Bg = gB(2); Bo = gB(3); BL = gB(4);
  } else {
    const float* Wi = (w == 1) ? Wih1 : Wih2;
    const float* Wh = (w == 1) ? Whh1 : Whh2;
    const float* bi = (w == 1) ? bih1 : bih2;
    const float* bh = (w == 1) ? bhh1 : bhh2;
    auto gA = [&](int T, int c) {
      int row = rowmap(T, n);
      f16x8 r;
#pragma unroll
      for (int j = 0; j < 8; ++j) {
        int k = c * 32 + q * 8 + j;
        float v = (k < 20) ? Wi[row * 20 + k] : (k < 40 ? Wh[row * 20 + k - 20] : 0.f);
        r[j] = (f16)v;
      }
      return r;
    };
    Fa0 = gA(0, 0); Fb0 = gA(0, 1);
    Fa1 = gA(1, 0); Fb1 = gA(1, 1);
    Fa2 = gA(2, 0); Fb2 = gA(2, 1);
    Fa3 = gA(3, 0); Fb3 = gA(3, 1);
    Fa4 = gA(4, 0); Fb4 = gA(4, 1);
    auto gB = [&](int T) {
      f32x4 r;
#pragma unroll
      for (int j = 0; j < 4; ++j) { int row = rowmap(T, q * 4 + j); r[j] = bi[row] + bh[row]; }
      return r;
    };
    Bi = gB(0); Bf = gB(1); Bg = gB(2); Bo = gB(3); BL = gB(4);
  }

  // x prefetch (wave0 only): dwordx4 = 2 timesteps per pair-block.
  // pair p covers t=2p (lanes q0,q1: floats 0..7) and t=2p+1 (lanes q2,q3).
  const float* xb = x + (size_t)(blockIdx.x * 16 + n) * (T_LEN * 8) + 4 * q;
  f32x4 xA{}, xB{};
  if (w == 0) {
    xA = *(const f32x4*)(xb);        // pair 0 (t0,t1)
    xB = *(const f32x4*)(xb + 16);   // pair 1 (t2,t3)
  }

  // ---- skewed, wave-specialized main loop ----
#pragma unroll 1
  for (int i = 0; i <= T_LEN + 1; ++i) {
    asm volatile("" ::: "memory");   // pin LDS loads in-loop (R4 fix)
    if (w == 0) {
      if (i < T_LEN) {
        // stage x(i): holder lanes are q{0,1} on even i, q{2,3} on odd i
        if ((q >> 1) == (i & 1)) {
          f16x4 xh;
          xh[0] = (f16)xA[0]; xh[1] = (f16)xA[1]; xh[2] = (f16)xA[2]; xh[3] = (f16)xA[3];
          *(f16x4*)&zT0[n * 32 + SWZ0(n, 4 * (q & 1))] = xh;
        }
        if (i & 1) {                 // pair consumed: rotate, prefetch 2 ahead
          xA = xB;
          int pn = (i >> 1) + 2;
          if (pn > (T_LEN / 2 - 1)) pn = T_LEN / 2 - 1;
          xB = *(const f32x4*)(xb + pn * 16);
        }
        // L0(t=i)
        f16x8 b0 = *(const f16x8*)&zT0[n * 32 + SWZ0(n, q * 8)];
        f32x4 di = MFMA(Fa0, b0, Bi), df = MFMA(Fa1, b0, Bf),
              dg = MFMA(Fa2, b0, Bg), dn = MFMA(Fa3, b0, Bo),
              dl = MFMA(Fa4, b0, BL);
        f16x4 hv; CELLS4(di, df, dg, dn, hv)
        f16* d1 = &zT1[i & 1][0];
        *(f16x4*)&zT0[n * 32 + SWZ0(n, 8 + q * 4)] = hv;   // self (in-order)
        *(f16x4*)&d1[n * 64 + SWZ1(n, q * 4)] = hv;        // publish h0(i)
        f16 hl; CELL_L(dl, hl, gbuf[0])
        zT0[n * 32 + SWZ0(n, 24 + q)] = hl;
        d1[n * 64 + SWZ1(n, 16 + q)] = hl;
      }
    } else if (w == 1) {
      if (i >= 1 && i <= T_LEN) {
        // L1(t=i-1): reads h0(i-1), h1(i-2) from parity (i-1)&1
        const f16* src = &zT1[(i - 1) & 1][0];
        f16x8 ba = *(const f16x8*)&src[n * 64 + SWZ1(n, q * 8)];
        f16x8 bb = *(const f16x8*)&src[n * 64 + SWZ1(n, 32 + q * 8)];
        f32x4 di = MFMA(Fb0, bb, MFMA(Fa0, ba, Bi));
        f32x4 df = MFMA(Fb1, bb, MFMA(Fa1, ba, Bf));
        f32x4 dg = MFMA(Fb2, bb, MFMA(Fa2, ba, Bg));
        f32x4 dn = MFMA(Fb3, bb, MFMA(Fa3, ba, Bo));
        f32x4 dl = MFMA(Fb4, bb, MFMA(Fa4, ba, BL));
        f16x4 hv; CELLS4(di, df, dg, dn, hv)
        f16* d1 = &zT1[i & 1][0];
        f16* d2 = &zT2[i & 1][0];
        *(f16x4*)&d1[n * 64 + SWZ1(n, 20 + q * 4)] = hv;   // self h1(i-1)
        *(f16x4*)&d2[n * 64 + SWZ1(n, q * 4)] = hv;        // publish to L2
        f16 hl; CELL_L(dl, hl, gbuf[1])
        d1[n * 64 + SWZ1(n, 36 + q)] = hl;
        d2[n * 64 + SWZ1(n, 16 + q)] = hl;
      }
    } else {
      if (i >= 2) {
        // L2(t=i-2): reads h1(i-2), h2(i-3) from parity (i-1)&1
        const f16* src = &zT2[(i - 1) & 1][0];
        f16x8 ba = *(const f16x8*)&src[n * 64 + SWZ1(n, q * 8)];
        f16x8 bb = *(const f16x8*)&src[n * 64 + SWZ1(n, 32 + q * 8)];
        f32x4 di = MFMA(Fb0, bb, MFMA(Fa0, ba, Bi));
        f32x4 df = MFMA(Fb1, bb, MFMA(Fa1, ba, Bf));
        f32x4 dg = MFMA(Fb2, bb, MFMA(Fa2, ba, Bg));
        f32x4 dn = MFMA(Fb3, bb, MFMA(Fa3, ba, Bo));
        f32x4 dl = MFMA(Fb4, bb, MFMA(Fa4, ba, BL));
        f16x4 hv; CELLS4(di, df, dg, dn, hv)
        f16* d2 = &zT2[i & 1][0];
        *(f16x4*)&d2[n * 64 + SWZ1(n, 20 + q * 4)] = hv;   // self h2(i-2)
        f16 hl; CELL_L(dl, hl, gbuf[2])
        d2[n * 64 + SWZ1(n, 36 + q)] = hl;
      }
    }
    // LDS-only barrier: cross-wave handoff needs lgkmcnt(0) visibility, NOT
    // vmcnt(0) — wave0's in-flight x loads stay outstanding across it.
    asm volatile("s_waitcnt lgkmcnt(0)\n\ts_barrier" ::: "memory");
  }

  // ---- FC head (wave2; h2(T-1) is in zT2[(T+1)&1], written by wave2) ----
  if (w == 2) {
    const f16* hb = &zT2[(T_LEN + 1) & 1][0];
    f16x4 hv0 = *(const f16x4*)&hb[n * 64 + SWZ1(n, 20)];
    f16x4 hv1 = *(const f16x4*)&hb[n * 64 + SWZ1(n, 24)];
    f16x4 hv2 = *(const f16x4*)&hb[n * 64 + SWZ1(n, 28)];
    f16x4 hv3 = *(const f16x4*)&hb[n * 64 + SWZ1(n, 32)];
    f16x4 hv4 = *(const f16x4*)&hb[n * 64 + SWZ1(n, 36)];
    float p = 0.f;
#pragma unroll
    for (int i = 0; i < 5; ++i) {
      int d = q * 5 + i;
      const float* wr = fc1w + d * 20;
      float s = fc1b[d]
        + wr[0]  * (float)hv0[0] + wr[1]  * (float)hv0[1] + wr[2]  * (float)hv0[2] + wr[3]  * (float)hv0[3]
        + wr[4]  * (float)hv1[0] + wr[5]  * (float)hv1[1] + wr[6]  * (float)hv1[2] + wr[7]  * (float)hv1[3]
        + wr[8]  * (float)hv2[0] + wr[9]  * (float)hv2[1] + wr[10] * (float)hv2[2] + wr[11] * (float)hv2[3]
        + wr[12] * (float)hv3[0] + wr[13] * (float)hv3[1] + wr[14] * (float)hv3[2] + wr[15] * (float)hv3[3]
        + wr[16] * (float)hv4[0] + wr[17] * (float)hv4[1] + wr[18] * (float)hv4[2] + wr[19] * (float)hv4[3];
      p += fc2w[d] * fmaxf(s, 0.f);
    }
    pbuf[n * 4 + q] = p;            // wave-internal, in-order
    if (q == 0) {
      f32x4 pv = *(const f32x4*)&pbuf[n * 4];
      out[blockIdx.x * 16 + n] = pv[0] + pv[1] + pv[2] + pv[3] + fc2b[0];
    }
  }
}

extern "C" void kernel_launch(void* const* d_in, const int* in_sizes, int n_in,
                              void* d_out, int out_size, void* d_ws, size_t ws_size,
                              hipStream_t stream) {
  const float* x    = (const float*)d_in[0];
  const float* Wih0 = (const float*)d_in[1];
  const float* Whh0 = (const float*)d_in[2];
  const float* bih0 = (const float*)d_in[3];
  const float* bhh0 = (const float*)d_in[4];
  const float* Wih1 = (const float*)d_in[5];
  const float* Whh1 = (const float*)d_in[6];
  const float* bih1 = (const float*)d_in[7];
  const float* bhh1 = (const float*)d_in[8];
  const float* Wih2 = (const float*)d_in[9];
  const float* Whh2 = (const float*)d_in[10];
  const float* bih2 = (const float*)d_in[11];
  const float* bhh2 = (const float*)d_in[12];
  const float* fc1w = (const float*)d_in[13];
  const float* fc1b = (const float*)d_in[14];
  const float* fc2w = (const float*)d_in[15];
  const float* fc2b = (const float*)d_in[16];
  float* out = (float*)d_out;

  hipLaunchKernelGGL(lstm3_ws_kernel, dim3(8192 / 16), dim3(192), 0, stream,
                     x, Wih0, Whh0, bih0, bhh0,
                     Wih1, Whh1, bih1, bhh1,
                     Wih2, Whh2, bih2, bhh2,
                     fc1w, fc1b, fc2w, fc2b, out);
}

// Round 2
// 415.182 us; speedup vs baseline: 1.1653x; 1.1154x over previous
//
#include <hip/hip_runtime.h>

// 3-layer LSTM (B=8192, T=336, F=8, H=20) + FC(20->20 relu) + FC(20->1).
//
// Round 10 (on R9): latency/convoy attack.
//  a) 2 TIMESTEPS PER BARRIER: 338 -> 170 barriers. Wave w still owns layer
//     w; skew is in units of 2 steps. Intra-iter A->B handoff is in-wave
//     (lgkm-ordered LDS), not a 3-wave barrier. Rows are now
//     [h_in 20 | pad12 | h_self 20 | pad12] (64 f16) so the A-operand k-space
//     is [h_in | 0...] / [h_self | 0...] and sub-B's dependency is one b128.
//  b) LEFTOVER TILE UNIT-MAJOR: rowmap(T=4,m) = (m&3)*20+16+(m>>2) puts all
//     4 gates of unit 16+q in-lane -> CELL_L's gbuf LDS bounce (~250cy serial
//     tail/iter) deleted; all 5 cells are pure-register.
//  c) x staging: one dwordx4 = 2 timesteps/lane/iter, depth-2 prefetch kept.
//     zT0 widened to 128B rows (SWZ1) so b128 reads are 2-way (free).
//  Kept: lgkm-only barrier (R9a), XOR swizzles (R9c), LICM clobber (R4).
//
// MFMA layouts (m89/m120-verified): A[m][k]: m=lane&15,k=(lane>>4)*8+j;
// B[k][n]: n=lane&15,k=(lane>>4)*8+j; D[m][n]: n=lane&15,m=(lane>>4)*4+reg.

#define T_LEN 336
#define NJ 169   // j = 0..169; w0: t=2j,2j+1 (j<=167); w1: 2j-2,2j-1; w2: 2j-4,2j-3

typedef _Float16 f16;
typedef _Float16 f16x4 __attribute__((ext_vector_type(4)));
typedef _Float16 f16x8 __attribute__((ext_vector_type(8)));
typedef float f32x4 __attribute__((ext_vector_type(4)));

#define MFMA(a, b, c) __builtin_amdgcn_mfma_f32_16x16x32_f16((a), (b), (c), 0, 0, 0)

// 16B-slot XOR swizzle for 64-f16 (128B) rows
#define SWZ1(n, c) ((c) ^ (((n) & 7) << 3))

__device__ __forceinline__ float sigm(float x) {
  return __builtin_amdgcn_rcpf(1.0f + __builtin_amdgcn_exp2f(-1.4426950408889634f * x));
}
__device__ __forceinline__ float tanh_fast(float x) {
  return 2.0f * __builtin_amdgcn_rcpf(1.0f + __builtin_amdgcn_exp2f(-2.8853900817779268f * x)) - 1.0f;
}

// 5 in-lane cells: tiles 0..3 gate-aligned (reg r = unit 4q+r), tile 4
// unit-major (reg r = gate r of unit 16+q).
#define CELLS5(DI, DF, DG, DO, DL, HV, HL) {                                                \
  { float i_=sigm((DI)[0]), f_=sigm((DF)[0]), g_=tanh_fast((DG)[0]), o_=sigm((DO)[0]);      \
    c0 = f_*c0 + i_*g_; (HV)[0] = (f16)(o_*tanh_fast(c0)); }                                \
  { float i_=sigm((DI)[1]), f_=sigm((DF)[1]), g_=tanh_fast((DG)[1]), o_=sigm((DO)[1]);      \
    c1 = f_*c1 + i_*g_; (HV)[1] = (f16)(o_*tanh_fast(c1)); }                                \
  { float i_=sigm((DI)[2]), f_=sigm((DF)[2]), g_=tanh_fast((DG)[2]), o_=sigm((DO)[2]);      \
    c2 = f_*c2 + i_*g_; (HV)[2] = (f16)(o_*tanh_fast(c2)); }                                \
  { float i_=sigm((DI)[3]), f_=sigm((DF)[3]), g_=tanh_fast((DG)[3]), o_=sigm((DO)[3]);      \
    c3 = f_*c3 + i_*g_; (HV)[3] = (f16)(o_*tanh_fast(c3)); }                                \
  { float i_=sigm((DL)[0]), f_=sigm((DL)[1]), g_=tanh_fast((DL)[2]), o_=sigm((DL)[3]);      \
    cL = f_*cL + i_*g_; (HL) = (f16)(o_*tanh_fast(cL)); } }

// L1/L2 step: src row [h_in 20|pad|h_self 20|pad]; writes h into DSELF c32..51
// and (optionally) publishes into DPUB c0..19.
#define MIDSTEP(SRC, DSELF, DPUB) {                                                         \
  const f16* s_ = (SRC);                                                                    \
  f16x8 ba = *(const f16x8*)&s_[n * 64 + SWZ1(n, q * 8)];                                   \
  f16x8 bb = *(const f16x8*)&s_[n * 64 + SWZ1(n, 32 + q * 8)];                              \
  f32x4 di = MFMA(Fb0, bb, MFMA(Fa0, ba, Bi));                                              \
  f32x4 df = MFMA(Fb1, bb, MFMA(Fa1, ba, Bf));                                              \
  f32x4 dg = MFMA(Fb2, bb, MFMA(Fa2, ba, Bg));                                              \
  f32x4 dn = MFMA(Fb3, bb, MFMA(Fa3, ba, Bo));                                              \
  f32x4 dl = MFMA(Fb4, bb, MFMA(Fa4, ba, BL));                                              \
  f16x4 hv; f16 hl; CELLS5(di, df, dg, dn, dl, hv, hl)                                      \
  f16* ds_ = (DSELF);                                                                       \
  *(f16x4*)&ds_[n * 64 + SWZ1(n, 32 + q * 4)] = hv;                                         \
  ds_[n * 64 + SWZ1(n, 48 + q)] = hl;                                                       \
  f16* dp_ = (DPUB);                                                                        \
  if (dp_) { *(f16x4*)&dp_[n * 64 + SWZ1(n, q * 4)] = hv;                                   \
             dp_[n * 64 + SWZ1(n, 16 + q)] = hl; } }

// L0 step: src row [x 8 | h0 20 | pad] (zT0); h -> DSELF c8..27, publish c0..19
#define L0STEP(SRC, DSELF, DPUB) {                                                          \
  const f16* s_ = (SRC);                                                                    \
  f16x8 b0 = *(const f16x8*)&s_[n * 64 + SWZ1(n, q * 8)];                                   \
  f32x4 di = MFMA(Fa0, b0, Bi), df = MFMA(Fa1, b0, Bf), dg = MFMA(Fa2, b0, Bg),             \
        dn = MFMA(Fa3, b0, Bo), dl = MFMA(Fa4, b0, BL);                                     \
  f16x4 hv; f16 hl; CELLS5(di, df, dg, dn, dl, hv, hl)                                      \
  f16* ds_ = (DSELF);                                                                       \
  *(f16x4*)&ds_[n * 64 + SWZ1(n, 8 + q * 4)] = hv;                                          \
  ds_[n * 64 + SWZ1(n, 24 + q)] = hl;                                                       \
  f16* dp_ = (DPUB);                                                                        \
  *(f16x4*)&dp_[n * 64 + SWZ1(n, q * 4)] = hv;                                              \
  dp_[n * 64 + SWZ1(n, 16 + q)] = hl; }

__global__ __launch_bounds__(192, 2) void lstm3_ws_kernel(
    const float* __restrict__ x,
    const float* __restrict__ Wih0, const float* __restrict__ Whh0,
    const float* __restrict__ bih0, const float* __restrict__ bhh0,
    const float* __restrict__ Wih1, const float* __restrict__ Whh1,
    const float* __restrict__ bih1, const float* __restrict__ bhh1,
    const float* __restrict__ Wih2, const float* __restrict__ Whh2,
    const float* __restrict__ bih2, const float* __restrict__ bhh2,
    const float* __restrict__ fc1w, const float* __restrict__ fc1b,
    const float* __restrict__ fc2w, const float* __restrict__ fc2b,
    float* __restrict__ out)
{
  // sub-rows: [0]=even-t slot (A), [1]=odd-t slot (B)
  __shared__ __align__(16) f16 zT0[2][16 * 64];     // wave0: [x 8|h0 20|pad]
  __shared__ __align__(16) f16 zT1[2][2][16 * 64];  // parity,sub: [h0|pad|h1|pad]
  __shared__ __align__(16) f16 zT2[2][2][16 * 64];  // parity,sub: [h1|pad|h2|pad]
  __shared__ __align__(16) float pbuf[64];          // fc2 partials

  const int tid  = threadIdx.x;
  const int w    = tid >> 6;        // wave id = layer id
  const int lane = tid & 63;
  const int n = lane & 15;          // batch elem (N index)
  const int q = lane >> 4;          // quad

  // ---- zero z buffers (h(.)=0, c implicit 0, pads 0) ----
  {
    f16x8 zer;
#pragma unroll
    for (int j = 0; j < 8; ++j) zer[j] = (f16)0.f;
    for (int i = tid; i < 256; i += 192) ((f16x8*)&zT0[0][0])[i] = zer;
    for (int i = tid; i < 512; i += 192) ((f16x8*)&zT1[0][0][0])[i] = zer;
    for (int i = tid; i < 512; i += 192) ((f16x8*)&zT2[0][0][0])[i] = zer;
  }
  __syncthreads();

  // ---- per-wave register-resident fragments ----
  // tiles 0..3: gate T, units 0..15. tile 4: UNIT-MAJOR leftover:
  // row = (m&3)*20 + 16 + (m>>2)  -> lane(q,n) reg r = gate r, unit 16+q.
  auto rowmap = [](int T, int m) { return T < 4 ? T * 20 + m : (m & 3) * 20 + 16 + (m >> 2); };

  f16x8 Fa0{}, Fa1{}, Fa2{}, Fa3{}, Fa4{};   // k-chunk 0 (w0: full [x|h] K)
  f16x8 Fb0{}, Fb1{}, Fb2{}, Fb3{}, Fb4{};   // k-chunk 1 (h_self; unused w0)
  f32x4 Bi{}, Bf{}, Bg{}, Bo{}, BL{};
  float c0 = 0.f, c1 = 0.f, c2 = 0.f, c3 = 0.f, cL = 0.f;

  if (w == 0) {
    auto gA0 = [&](int T) {
      int row = rowmap(T, n);
      f16x8 r;
#pragma unroll
      for (int j = 0; j < 8; ++j) {
        int k = q * 8 + j;
        float v = (k < 8) ? Wih0[row * 8 + k] : (k < 28 ? Whh0[row * 20 + k - 8] : 0.f);
        r[j] = (f16)v;
      }
      return r;
    };
    Fa0 = gA0(0); Fa1 = gA0(1); Fa2 = gA0(2); Fa3 = gA0(3); Fa4 = gA0(4);
    auto gB = [&](int T) {
      f32x4 r;
#pragma unroll
      for (int j = 0; j < 4; ++j) { int row = rowmap(T, q * 4 + j); r[j] = bih0[row] + bhh0[row]; }
      return r;
    };
    Bi = gB(0); Bf = gB(1); Bg = gB(2); Bo = gB(3); BL = gB(4);
  } else {
    const float* Wi = (w == 1) ? Wih1 : Wih2;
    const float* Wh = (w == 1) ? Whh1 : Whh2;
    const float* bi = (w == 1) ? bih1 : bih2;
    const float* bh = (w == 1) ? bhh1 : bhh2;
    // chunk 0 covers k=0..31 = [h_in 20 | 0 pad]; chunk 1 = [h_self 20 | 0]
    auto gA = [&](int T, int c) {
      int row = rowmap(T, n);
      const float* W = c ? Wh : Wi;
      f16x8 r;
#pragma unroll
      for (int j = 0; j < 8; ++j) {
        int k = q * 8 + j;
        r[j] = (f16)((k < 20) ? W[row * 20 + k] : 0.f);
      }
      return r;
    };
    Fa0 = gA(0, 0); Fb0 = gA(0, 1);
    Fa1 = gA(1, 0); Fb1 = gA(1, 1);
    Fa2 = gA(2, 0); Fb2 = gA(2, 1);
    Fa3 = gA(3, 0); Fb3 = gA(3, 1);
    Fa4 = gA(4, 0); Fb4 = gA(4, 1);
    auto gB = [&](int T) {
      f32x4 r;
#pragma unroll
      for (int j = 0; j < 4; ++j) { int row = rowmap(T, q * 4 + j); r[j] = bi[row] + bh[row]; }
      return r;
    };
    Bi = gB(0); Bf = gB(1); Bg = gB(2); Bo = gB(3); BL = gB(4);
  }

  // x prefetch (wave0): one dwordx4 per iter = pair block of 2 timesteps.
  // pair p floats 16p..16p+15: q0,q1 -> t=2p f0..7; q2,q3 -> t=2p+1 f0..7.
  const float* xb = x + (size_t)(blockIdx.x * 16 + n) * (T_LEN * 8) + 4 * q;
  f32x4 xA{}, xB{};
  if (w == 0) {
    xA = *(const f32x4*)(xb);        // pair 0
    xB = *(const f32x4*)(xb + 16);   // pair 1
  }

  // ---- main loop: 2 timesteps per barrier ----
#pragma unroll 1
  for (int j = 0; j <= NJ; ++j) {
    asm volatile("" ::: "memory");   // pin LDS traffic in-loop (R4 fix)
    const int wp = j & 1, rp = wp ^ 1;
    if (w == 0) {
      if (j <= 167) {
        // stage x pair j: sub=q>>1, cols 4*(q&1)..+3
        f16x4 xh;
        xh[0] = (f16)xA[0]; xh[1] = (f16)xA[1]; xh[2] = (f16)xA[2]; xh[3] = (f16)xA[3];
        *(f16x4*)&zT0[q >> 1][n * 64 + SWZ1(n, 4 * (q & 1))] = xh;
        xA = xB;
        int pn = j + 2; if (pn > 167) pn = 167;
        xB = *(const f32x4*)(xb + (size_t)pn * 16);
        L0STEP(&zT0[0][0], &zT0[1][0], &zT1[wp][0][0])   // t=2j   (h0 -> rowB)
        L0STEP(&zT0[1][0], &zT0[0][0], &zT1[wp][1][0])   // t=2j+1 (h0 -> rowA, next iter)
      }
    } else if (w == 1) {
      if (j >= 1 && j <= 168) {
        MIDSTEP(&zT1[rp][0][0], &zT1[rp][1][0], &zT2[wp][0][0])  // t=2j-2
        MIDSTEP(&zT1[rp][1][0], &zT1[wp][0][0], &zT2[wp][1][0])  // t=2j-1
      }
    } else {
      if (j >= 2) {
        MIDSTEP(&zT2[rp][0][0], &zT2[rp][1][0], (f16*)nullptr)   // t=2j-4
        MIDSTEP(&zT2[rp][1][0], &zT2[wp][0][0], (f16*)nullptr)   // t=2j-3
      }
    }
    // LDS-only barrier: cross-wave handoff needs lgkmcnt(0), NOT vmcnt(0) —
    // wave0's in-flight x loads stay outstanding across it (R9 fix).
    asm volatile("s_waitcnt lgkmcnt(0)\n\ts_barrier" ::: "memory");
  }

  // ---- FC head (wave2): h2(335) written at j=169 (wp=1) sub-B -> zT2[1][0] c32..51
  if (w == 2) {
    const f16* hb = &zT2[1][0][0];
    f16x4 hv0 = *(const f16x4*)&hb[n * 64 + SWZ1(n, 32)];
    f16x4 hv1 = *(const f16x4*)&hb[n * 64 + SWZ1(n, 36)];
    f16x4 hv2 = *(const f16x4*)&hb[n * 64 + SWZ1(n, 40)];
    f16x4 hv3 = *(const f16x4*)&hb[n * 64 + SWZ1(n, 44)];
    f16x4 hv4 = *(const f16x4*)&hb[n * 64 + SWZ1(n, 48)];
    float p = 0.f;
#pragma unroll
    for (int i = 0; i < 5; ++i) {
      int d = q * 5 + i;
      const float* wr = fc1w + d * 20;
      float s = fc1b[d]
        + wr[0]  * (float)hv0[0] + wr[1]  * (float)hv0[1] + wr[2]  * (float)hv0[2] + wr[3]  * (float)hv0[3]
        + wr[4]  * (float)hv1[0] + wr[5]  * (float)hv1[1] + wr[6]  * (float)hv1[2] + wr[7]  * (float)hv1[3]
        + wr[8]  * (float)hv2[0] + wr[9]  * (float)hv2[1] + wr[10] * (float)hv2[2] + wr[11] * (float)hv2[3]
        + wr[12] * (float)hv3[0] + wr[13] * (float)hv3[1] + wr[14] * (float)hv3[2] + wr[15] * (float)hv3[3]
        + wr[16] * (float)hv4[0] + wr[17] * (float)hv4[1] + wr[18] * (float)hv4[2] + wr[19] * (float)hv4[3];
      p += fc2w[d] * fmaxf(s, 0.f);
    }
    pbuf[n * 4 + q] = p;            // wave-internal, in-order
    if (q == 0) {
      f32x4 pv = *(const f32x4*)&pbuf[n * 4];
      out[blockIdx.x * 16 + n] = pv[0] + pv[1] + pv[2] + pv[3] + fc2b[0];
    }
  }
}

extern "C" void kernel_launch(void* const* d_in, const int* in_sizes, int n_in,
                              void* d_out, int out_size, void* d_ws, size_t ws_size,
                              hipStream_t stream) {
  const float* x    = (const float*)d_in[0];
  const float* Wih0 = (const float*)d_in[1];
  const float* Whh0 = (const float*)d_in[2];
  const float* bih0 = (const float*)d_in[3];
  const float* bhh0 = (const float*)d_in[4];
  const float* Wih1 = (const float*)d_in[5];
  const float* Whh1 = (const float*)d_in[6];
  const float* bih1 = (const float*)d_in[7];
  const float* bhh1 = (const float*)d_in[8];
  const float* Wih2 = (const float*)d_in[9];
  const float* Whh2 = (const float*)d_in[10];
  const float* bih2 = (const float*)d_in[11];
  const float* bhh2 = (const float*)d_in[12];
  const float* fc1w = (const float*)d_in[13];
  const float* fc1b = (const float*)d_in[14];
  const float* fc2w = (const float*)d_in[15];
  const float* fc2b = (const float*)d_in[16];
  float* out = (float*)d_out;

  hipLaunchKernelGGL(lstm3_ws_kernel, dim3(8192 / 16), dim3(192), 0, stream,
                     x, Wih0, Whh0, bih0, bhh0,
                     Wih1, Whh1, bih1, bhh1,
                     Wih2, Whh2, bih2, bhh2,
                     fc1w, fc1b, fc2w, fc2b, out);
}

// Round 4
// 396.548 us; speedup vs baseline: 1.2200x; 1.0470x over previous
//
#include <hip/hip_runtime.h>

// 3-layer LSTM (B=8192, T=336, F=8, H=20) + FC(20->20 relu) + FC(20->1).
//
// Round 11 (on R10): convoy amortization + overlap. (Resubmit — previous
// bench died to container infra, not the kernel.)
//  a) 4 TIMESTEPS PER BARRIER: 170 -> 86 barriers. zT0 = 4 sub-slots ring
//     (substep s reads slot s [x(t)|h0(t-1)], writes h0 into slot (s+1)&3);
//     zT1/zT2 = [parity][4 sub-slots]. Cross-wave handoffs cross exactly one
//     barrier (skew in 4-step groups); in-wave chaining is lgkm-ordered.
//  b) HOISTED ba READS: all 4 h_in fragments readable at iter start -> the
//     h_in-chunk MFMAs of every substep are independent; only h_self-chunk
//     MFMA + cells serialize per substep.
//  c) s_setprio(1) during compute, (0) before the barrier: waves parked at
//     the barrier yield SIMD issue to waves still computing (T5, role-diverse
//     waves -- the attn-positive case, not the GEMM-lockstep null case).
//  Kept: lgkm-only barrier (R9), XOR swizzle (R9), unit-major leftover tile
//  (R10), 2-timestep dwordx4 x loads with depth-1-group prefetch, LICM pin.
//
// MFMA layouts (m89/m120-verified): A[m][k]: m=lane&15,k=(lane>>4)*8+j;
// B[k][n]: n=lane&15,k=(lane>>4)*8+j; D[m][n]: n=lane&15,m=(lane>>4)*4+reg.

#define T_LEN 336
#define NJ 85   // j=0..85; w0: group j (t=4j..4j+3, j<=83); w1: group j-1; w2: group j-2

typedef _Float16 f16;
typedef _Float16 f16x4 __attribute__((ext_vector_type(4)));
typedef _Float16 f16x8 __attribute__((ext_vector_type(8)));
typedef float f32x4 __attribute__((ext_vector_type(4)));

#define MFMA(a, b, c) __builtin_amdgcn_mfma_f32_16x16x32_f16((a), (b), (c), 0, 0, 0)

// 16B-slot XOR swizzle for 64-f16 (128B) rows
#define SWZ1(n, c) ((c) ^ (((n) & 7) << 3))

__device__ __forceinline__ float sigm(float x) {
  return __builtin_amdgcn_rcpf(1.0f + __builtin_amdgcn_exp2f(-1.4426950408889634f * x));
}
__device__ __forceinline__ float tanh_fast(float x) {
  return 2.0f * __builtin_amdgcn_rcpf(1.0f + __builtin_amdgcn_exp2f(-2.8853900817779268f * x)) - 1.0f;
}

// 5 in-lane cells: tiles 0..3 gate-aligned (reg r = unit 4q+r), tile 4
// unit-major (reg r = gate r of unit 16+q).
#define CELLS5(DI, DF, DG, DO, DL, HV, HL) {                                                \
  { float i_=sigm((DI)[0]), f_=sigm((DF)[0]), g_=tanh_fast((DG)[0]), o_=sigm((DO)[0]);      \
    c0 = f_*c0 + i_*g_; (HV)[0] = (f16)(o_*tanh_fast(c0)); }                                \
  { float i_=sigm((DI)[1]), f_=sigm((DF)[1]), g_=tanh_fast((DG)[1]), o_=sigm((DO)[1]);      \
    c1 = f_*c1 + i_*g_; (HV)[1] = (f16)(o_*tanh_fast(c1)); }                                \
  { float i_=sigm((DI)[2]), f_=sigm((DF)[2]), g_=tanh_fast((DG)[2]), o_=sigm((DO)[2]);      \
    c2 = f_*c2 + i_*g_; (HV)[2] = (f16)(o_*tanh_fast(c2)); }                                \
  { float i_=sigm((DI)[3]), f_=sigm((DF)[3]), g_=tanh_fast((DG)[3]), o_=sigm((DO)[3]);      \
    c3 = f_*c3 + i_*g_; (HV)[3] = (f16)(o_*tanh_fast(c3)); }                                \
  { float i_=sigm((DL)[0]), f_=sigm((DL)[1]), g_=tanh_fast((DL)[2]), o_=sigm((DL)[3]);      \
    cL = f_*cL + i_*g_; (HL) = (f16)(o_*tanh_fast(cL)); } }

// L1/L2 substep: BA = preloaded h_in fragment; SRC = slot base for bb
// (h_self, cols 32..51); SELF = dst slot base (h_self write, c32..51);
// PUB = publish slot base or nullptr (c0..19).
#define MSTEP(BA, SRC, SELF, PUB) {                                                         \
  f16x8 bb = *(const f16x8*)&(SRC)[n * 64 + SWZ1(n, 32 + q * 8)];                           \
  f32x4 di = MFMA(Fb0, bb, MFMA(Fa0, (BA), Bi));                                            \
  f32x4 df = MFMA(Fb1, bb, MFMA(Fa1, (BA), Bf));                                            \
  f32x4 dg = MFMA(Fb2, bb, MFMA(Fa2, (BA), Bg));                                            \
  f32x4 dn = MFMA(Fb3, bb, MFMA(Fa3, (BA), Bo));                                            \
  f32x4 dl = MFMA(Fb4, bb, MFMA(Fa4, (BA), BL));                                            \
  f16x4 hv; f16 hl; CELLS5(di, df, dg, dn, dl, hv, hl)                                      \
  f16* ds_ = (SELF);                                                                        \
  *(f16x4*)&ds_[n * 64 + SWZ1(n, 32 + q * 4)] = hv;                                         \
  ds_[n * 64 + SWZ1(n, 48 + q)] = hl;                                                       \
  f16* dp_ = (PUB);                                                                         \
  if (dp_) { *(f16x4*)&dp_[n * 64 + SWZ1(n, q * 4)] = hv;                                   \
             dp_[n * 64 + SWZ1(n, 16 + q)] = hl; } }

// L0 substep: read slot S [x(t) 8 | h0(t-1) 20 | pad4], write h0(t) into slot
// D (c8..27), publish into PUB (c0..19).
#define L0S(S, D, PUB) {                                                                    \
  f16x8 b0 = *(const f16x8*)&zT0[S][n * 64 + SWZ1(n, q * 8)];                               \
  f32x4 di = MFMA(Fa0, b0, Bi), df = MFMA(Fa1, b0, Bf), dg = MFMA(Fa2, b0, Bg),             \
        dn = MFMA(Fa3, b0, Bo), dl = MFMA(Fa4, b0, BL);                                     \
  f16x4 hv; f16 hl; CELLS5(di, df, dg, dn, dl, hv, hl)                                      \
  *(f16x4*)&zT0[D][n * 64 + SWZ1(n, 8 + q * 4)] = hv;                                       \
  zT0[D][n * 64 + SWZ1(n, 24 + q)] = hl;                                                    \
  f16* dp_ = (PUB);                                                                         \
  *(f16x4*)&dp_[n * 64 + SWZ1(n, q * 4)] = hv;                                              \
  dp_[n * 64 + SWZ1(n, 16 + q)] = hl; }

__global__ __launch_bounds__(192, 2) void lstm3_ws_kernel(
    const float* __restrict__ x,
    const float* __restrict__ Wih0, const float* __restrict__ Whh0,
    const float* __restrict__ bih0, const float* __restrict__ bhh0,
    const float* __restrict__ Wih1, const float* __restrict__ Whh1,
    const float* __restrict__ bih1, const float* __restrict__ bhh1,
    const float* __restrict__ Wih2, const float* __restrict__ Whh2,
    const float* __restrict__ bih2, const float* __restrict__ bhh2,
    const float* __restrict__ fc1w, const float* __restrict__ fc1b,
    const float* __restrict__ fc2w, const float* __restrict__ fc2b,
    float* __restrict__ out)
{
  __shared__ __align__(16) f16 zT0[4][16 * 64];     // slot s: [x(t) 8|h0(t-1) 20|pad]
  __shared__ __align__(16) f16 zT1[2][4][16 * 64];  // parity,sub: [h0 20|pad|h1 20|pad]
  __shared__ __align__(16) f16 zT2[2][4][16 * 64];  // parity,sub: [h1 20|pad|h2 20|pad]
  __shared__ __align__(16) float pbuf[64];          // fc2 partials

  const int tid  = threadIdx.x;
  const int w    = tid >> 6;        // wave id = layer id
  const int lane = tid & 63;
  const int n = lane & 15;          // batch elem (N index)
  const int q = lane >> 4;          // quad

  // ---- zero z buffers (h(.)=0, c implicit 0, pads 0) ----
  {
    f16x8 zer;
#pragma unroll
    for (int j = 0; j < 8; ++j) zer[j] = (f16)0.f;
    for (int i = tid; i < 512; i += 192)  ((f16x8*)&zT0[0][0])[i] = zer;
    for (int i = tid; i < 1024; i += 192) ((f16x8*)&zT1[0][0][0])[i] = zer;
    for (int i = tid; i < 1024; i += 192) ((f16x8*)&zT2[0][0][0])[i] = zer;
  }
  __syncthreads();

  // ---- per-wave register-resident fragments ----
  // tiles 0..3: gate T, units 0..15. tile 4: UNIT-MAJOR leftover:
  // row = (m&3)*20 + 16 + (m>>2)  -> lane(q,n) reg r = gate r, unit 16+q.
  auto rowmap = [](int T, int m) { return T < 4 ? T * 20 + m : (m & 3) * 20 + 16 + (m >> 2); };

  f16x8 Fa0{}, Fa1{}, Fa2{}, Fa3{}, Fa4{};   // k-chunk 0 (w0: full [x|h] K)
  f16x8 Fb0{}, Fb1{}, Fb2{}, Fb3{}, Fb4{};   // k-chunk 1 (h_self; unused w0)
  f32x4 Bi{}, Bf{}, Bg{}, Bo{}, BL{};
  float c0 = 0.f, c1 = 0.f, c2 = 0.f, c3 = 0.f, cL = 0.f;

  if (w == 0) {
    auto gA0 = [&](int T) {
      int row = rowmap(T, n);
      f16x8 r;
#pragma unroll
      for (int j = 0; j < 8; ++j) {
        int k = q * 8 + j;
        float v = (k < 8) ? Wih0[row * 8 + k] : (k < 28 ? Whh0[row * 20 + k - 8] : 0.f);
        r[j] = (f16)v;
      }
      return r;
    };
    Fa0 = gA0(0); Fa1 = gA0(1); Fa2 = gA0(2); Fa3 = gA0(3); Fa4 = gA0(4);
    auto gB = [&](int T) {
      f32x4 r;
#pragma unroll
      for (int j = 0; j < 4; ++j) { int row = rowmap(T, q * 4 + j); r[j] = bih0[row] + bhh0[row]; }
      return r;
    };
    Bi = gB(0); Bf = gB(1); Bg = gB(2); Bo = gB(3); BL = gB(4);
  } else {
    const float* Wi = (w == 1) ? Wih1 : Wih2;
    const float* Wh = (w == 1) ? Whh1 : Whh2;
    const float* bi = (w == 1) ? bih1 : bih2;
    const float* bh = (w == 1) ? bhh1 : bhh2;
    // chunk 0 covers k=0..31 = [h_in 20 | 0 pad]; chunk 1 = [h_self 20 | 0]
    auto gA = [&](int T, int c) {
      int row = rowmap(T, n);
      const float* W = c ? Wh : Wi;
      f16x8 r;
#pragma unroll
      for (int j = 0; j < 8; ++j) {
        int k = q * 8 + j;
        r[j] = (f16)((k < 20) ? W[row * 20 + k] : 0.f);
      }
      return r;
    };
    Fa0 = gA(0, 0); Fb0 = gA(0, 1);
    Fa1 = gA(1, 0); Fb1 = gA(1, 1);
    Fa2 = gA(2, 0); Fb2 = gA(2, 1);
    Fa3 = gA(3, 0); Fb3 = gA(3, 1);
    Fa4 = gA(4, 0); Fb4 = gA(4, 1);
    auto gB = [&](int T) {
      f32x4 r;
#pragma unroll
      for (int j = 0; j < 4; ++j) { int row = rowmap(T, q * 4 + j); r[j] = bi[row] + bh[row]; }
      return r;
    };
    Bi = gB(0); Bf = gB(1); Bg = gB(2); Bo = gB(3); BL = gB(4);
  }

  // x prefetch (wave0): dwordx4 = pair block of 2 timesteps.
  // pair p floats 16p..16p+15: q0,q1 -> t=2p f0..7; q2,q3 -> t=2p+1 f0..7.
  // group j = pairs 2j, 2j+1 (timesteps 4j..4j+3).
  const float* xb = x + (size_t)(blockIdx.x * 16 + n) * (T_LEN * 8) + 4 * q;
  f32x4 xA{}, xB{};
  if (w == 0) {
    xA = *(const f32x4*)(xb);        // pair 0
    xB = *(const f32x4*)(xb + 16);   // pair 1
  }

  // ---- main loop: 4 timesteps per barrier ----
#pragma unroll 1
  for (int j = 0; j <= NJ; ++j) {
    asm volatile("" ::: "memory");   // pin LDS traffic in-loop (R4 fix)
    __builtin_amdgcn_s_setprio(1);   // computing waves outrank barrier-parked
    const int wp = j & 1, rp = wp ^ 1;
    if (w == 0) {
      if (j <= 83) {
        // stage x group j: pair 2j -> slots 0/1, pair 2j+1 -> slots 2/3
        f16x4 xh;
        xh[0] = (f16)xA[0]; xh[1] = (f16)xA[1]; xh[2] = (f16)xA[2]; xh[3] = (f16)xA[3];
        *(f16x4*)&zT0[q >> 1][n * 64 + SWZ1(n, 4 * (q & 1))] = xh;
        xh[0] = (f16)xB[0]; xh[1] = (f16)xB[1]; xh[2] = (f16)xB[2]; xh[3] = (f16)xB[3];
        *(f16x4*)&zT0[2 + (q >> 1)][n * 64 + SWZ1(n, 4 * (q & 1))] = xh;
        // prefetch group j+1 (slack: one full iteration >> HBM latency)
        int g = (j + 1 > 83) ? 83 : j + 1;
        xA = *(const f32x4*)(xb + (size_t)(2 * g) * 16);
        xB = *(const f32x4*)(xb + (size_t)(2 * g + 1) * 16);
        f16* p1 = &zT1[wp][0][0];
        L0S(0, 1, p1 + 0 * 1024)   // t=4j
        L0S(1, 2, p1 + 1 * 1024)   // t=4j+1
        L0S(2, 3, p1 + 2 * 1024)   // t=4j+2
        L0S(3, 0, p1 + 3 * 1024)   // t=4j+3 (h0 -> slot0 for next iter)
      }
    } else if (w == 1) {
      if (j >= 1 && j <= 84) {
        // L1 group j-1: h_in = h0 (published last iter), h_self chained
        f16* s1 = &zT1[rp][0][0];
        f16x8 ba0 = *(const f16x8*)&s1[0 * 1024 + n * 64 + SWZ1(n, q * 8)];
        f16x8 ba1 = *(const f16x8*)&s1[1 * 1024 + n * 64 + SWZ1(n, q * 8)];
        f16x8 ba2 = *(const f16x8*)&s1[2 * 1024 + n * 64 + SWZ1(n, q * 8)];
        f16x8 ba3 = *(const f16x8*)&s1[3 * 1024 + n * 64 + SWZ1(n, q * 8)];
        f16* p2 = &zT2[wp][0][0];
        MSTEP(ba0, s1 + 0 * 1024, s1 + 1 * 1024, p2 + 0 * 1024)
        MSTEP(ba1, s1 + 1 * 1024, s1 + 2 * 1024, p2 + 1 * 1024)
        MSTEP(ba2, s1 + 2 * 1024, s1 + 3 * 1024, p2 + 2 * 1024)
        MSTEP(ba3, s1 + 3 * 1024, &zT1[wp][0][0], p2 + 3 * 1024)
      }
    } else {
      if (j >= 2) {
        // L2 group j-2
        f16* s2 = &zT2[rp][0][0];
        f16x8 ca0 = *(const f16x8*)&s2[0 * 1024 + n * 64 + SWZ1(n, q * 8)];
        f16x8 ca1 = *(const f16x8*)&s2[1 * 1024 + n * 64 + SWZ1(n, q * 8)];
        f16x8 ca2 = *(const f16x8*)&s2[2 * 1024 + n * 64 + SWZ1(n, q * 8)];
        f16x8 ca3 = *(const f16x8*)&s2[3 * 1024 + n * 64 + SWZ1(n, q * 8)];
        MSTEP(ca0, s2 + 0 * 1024, s2 + 1 * 1024, (f16*)nullptr)
        MSTEP(ca1, s2 + 1 * 1024, s2 + 2 * 1024, (f16*)nullptr)
        MSTEP(ca2, s2 + 2 * 1024, s2 + 3 * 1024, (f16*)nullptr)
        MSTEP(ca3, s2 + 3 * 1024, &zT2[wp][0][0], (f16*)nullptr)
      }
    }
    __builtin_amdgcn_s_setprio(0);
    // LDS-only barrier: cross-wave handoff needs lgkmcnt(0), NOT vmcnt(0) —
    // wave0's in-flight x loads stay outstanding across it (R9 fix).
    asm volatile("s_waitcnt lgkmcnt(0)\n\ts_barrier" ::: "memory");
  }

  // ---- FC head (wave2): h2(335) written at j=85 (wp=1) substep3 -> zT2[1][0] c32..51
  if (w == 2) {
    const f16* hb = &zT2[1][0][0];
    f16x4 hv0 = *(const f16x4*)&hb[n * 64 + SWZ1(n, 32)];
    f16x4 hv1 = *(const f16x4*)&hb[n * 64 + SWZ1(n, 36)];
    f16x4 hv2 = *(const f16x4*)&hb[n * 64 + SWZ1(n, 40)];
    f16x4 hv3 = *(const f16x4*)&hb[n * 64 + SWZ1(n, 44)];
    f16x4 hv4 = *(const f16x4*)&hb[n * 64 + SWZ1(n, 48)];
    float p = 0.f;
#pragma unroll
    for (int i = 0; i < 5; ++i) {
      int d = q * 5 + i;
      const float* wr = fc1w + d * 20;
      float s = fc1b[d]
        + wr[0]  * (float)hv0[0] + wr[1]  * (float)hv0[1] + wr[2]  * (float)hv0[2] + wr[3]  * (float)hv0[3]
        + wr[4]  * (float)hv1[0] + wr[5]  * (float)hv1[1] + wr[6]  * (float)hv1[2] + wr[7]  * (float)hv1[3]
        + wr[8]  * (float)hv2[0] + wr[9]  * (float)hv2[1] + wr[10] * (float)hv2[2] + wr[11] * (float)hv2[3]
        + wr[12] * (float)hv3[0] + wr[13] * (float)hv3[1] + wr[14] * (float)hv3[2] + wr[15] * (float)hv3[3]
        + wr[16] * (float)hv4[0] + wr[17] * (float)hv4[1] + wr[18] * (float)hv4[2] + wr[19] * (float)hv4[3];
      p += fc2w[d] * fmaxf(s, 0.f);
    }
    pbuf[n * 4 + q] = p;            // wave-internal, in-order
    if (q == 0) {
      f32x4 pv = *(const f32x4*)&pbuf[n * 4];
      out[blockIdx.x * 16 + n] = pv[0] + pv[1] + pv[2] + pv[3] + fc2b[0];
    }
  }
}

extern "C" void kernel_launch(void* const* d_in, const int* in_sizes, int n_in,
                              void* d_out, int out_size, void* d_ws, size_t ws_size,
                              hipStream_t stream) {
  const float* x    = (const float*)d_in[0];
  const float* Wih0 = (const float*)d_in[1];
  const float* Whh0 = (const float*)d_in[2];
  const float* bih0 = (const float*)d_in[3];
  const float* bhh0 = (const float*)d_in[4];
  const float* Wih1 = (const float*)d_in[5];
  const float* Whh1 = (const float*)d_in[6];
  const float* bih1 = (const float*)d_in[7];
  const float* bhh1 = (const float*)d_in[8];
  const float* Wih2 = (const float*)d_in[9];
  const float* Whh2 = (const float*)d_in[10];
  const float* bih2 = (const float*)d_in[11];
  const float* bhh2 = (const float*)d_in[12];
  const float* fc1w = (const float*)d_in[13];
  const float* fc1b = (const float*)d_in[14];
  const float* fc2w = (const float*)d_in[15];
  const float* fc2b = (const float*)d_in[16];
  float* out = (float*)d_out;

  hipLaunchKernelGGL(lstm3_ws_kernel, dim3(8192 / 16), dim3(192), 0, stream,
                     x, Wih0, Whh0, bih0, bhh0,
                     Wih1, Whh1, bih1, bhh1,
                     Wih2, Whh2, bih2, bhh2,
                     fc1w, fc1b, fc2w, fc2b, out);
}

// Round 5
// 387.509 us; speedup vs baseline: 1.2485x; 1.0233x over previous
//
#include <hip/hip_runtime.h>

// 3-layer LSTM (B=8192, T=336, F=8, H=20) + FC(20->20 relu) + FC(20->1).
//
// Round 12 (on R11): VALU-issue + recurrent-chain attack.
//  a) PRESCALED GATES: W,b rows pre-multiplied by -log2e (i,f,o) / -2log2e
//     (g) at fragment load -> sigm/tanh drop their input mul:
//     sigm_p(y)=rcp(1+exp2(y)), tanh_p likewise. -4 v_mul per cell.
//  b) REGISTER h_self (w1/w2): the recurrent B-fragment is rebuilt in-reg
//     from the previous substep's cell outputs via 8 ds_bpermute + 2 packs
//     + 2 selects (lane(n,q) needs h[8q..8q+7]; k>=20 garbage hits zero
//     weight rows). Kills 2 self ds_writes + 1 ds_read + lgkm RAW turnaround
//     per substep on the serial chain. w0 keeps its LDS ring (lightest wave).
//     w2 writes final h2 to LDS once after the loop for the FC head.
//  Kept: 4 ts/barrier + hoisted ba reads + setprio (R11), lgkm-only barrier
//  (R9), XOR swizzle (R9), unit-major leftover tile (R10), LICM pin (R4).
//
// MFMA layouts (m89/m120-verified): A[m][k]: m=lane&15,k=(lane>>4)*8+j;
// B[k][n]: n=lane&15,k=(lane>>4)*8+j; D[m][n]: n=lane&15,m=(lane>>4)*4+reg.

#define T_LEN 336
#define NJ 85   // j=0..85; w0: group j (t=4j..4j+3, j<=83); w1: group j-1; w2: group j-2

typedef _Float16 f16;
typedef _Float16 f16x4 __attribute__((ext_vector_type(4)));
typedef _Float16 f16x8 __attribute__((ext_vector_type(8)));
typedef float f32x4 __attribute__((ext_vector_type(4)));
typedef int i32x2 __attribute__((ext_vector_type(2)));
typedef int i32x4 __attribute__((ext_vector_type(4)));

#define MFMA(a, b, c) __builtin_amdgcn_mfma_f32_16x16x32_f16((a), (b), (c), 0, 0, 0)

// 16B-slot XOR swizzle for 64-f16 (128B) rows
#define SWZ1(n, c) ((c) ^ (((n) & 7) << 3))

#define KS1 1.4426950408889634f   // log2(e)
#define KS2 2.8853900817779268f   // 2*log2(e)

// prescaled activations: y arrives as -KS1*x (sigm) / -KS2*x (tanh)
__device__ __forceinline__ float sigm_p(float y) {
  return __builtin_amdgcn_rcpf(1.0f + __builtin_amdgcn_exp2f(y));
}
__device__ __forceinline__ float tanh_p(float y) {
  return 2.0f * __builtin_amdgcn_rcpf(1.0f + __builtin_amdgcn_exp2f(y)) - 1.0f;
}
__device__ __forceinline__ float tanh_fast(float x) {   // raw arg (cell state)
  return 2.0f * __builtin_amdgcn_rcpf(1.0f + __builtin_amdgcn_exp2f(-KS2 * x)) - 1.0f;
}

// 5 in-lane cells; gate inputs arrive PRESCALED (see gA/gB loaders).
#define CELLS5(DI, DF, DG, DO, DL, HV, HL) {                                                \
  { float i_=sigm_p((DI)[0]), f_=sigm_p((DF)[0]), g_=tanh_p((DG)[0]), o_=sigm_p((DO)[0]);   \
    c0 = f_*c0 + i_*g_; (HV)[0] = (f16)(o_*tanh_fast(c0)); }                                \
  { float i_=sigm_p((DI)[1]), f_=sigm_p((DF)[1]), g_=tanh_p((DG)[1]), o_=sigm_p((DO)[1]);   \
    c1 = f_*c1 + i_*g_; (HV)[1] = (f16)(o_*tanh_fast(c1)); }                                \
  { float i_=sigm_p((DI)[2]), f_=sigm_p((DF)[2]), g_=tanh_p((DG)[2]), o_=sigm_p((DO)[2]);   \
    c2 = f_*c2 + i_*g_; (HV)[2] = (f16)(o_*tanh_fast(c2)); }                                \
  { float i_=sigm_p((DI)[3]), f_=sigm_p((DF)[3]), g_=tanh_p((DG)[3]), o_=sigm_p((DO)[3]);   \
    c3 = f_*c3 + i_*g_; (HV)[3] = (f16)(o_*tanh_fast(c3)); }                                \
  { float i_=sigm_p((DL)[0]), f_=sigm_p((DL)[1]), g_=tanh_p((DL)[2]), o_=sigm_p((DL)[3]);   \
    cL = f_*cL + i_*g_; (HL) = (f16)(o_*tanh_fast(cL)); } }

// L1/L2 substep, REGISTER h_self: rebuild bb from hvS/hlS via bpermute.
// lane(n,q) wants bb k=8q..8q+7 of [h_self 20 | pad12]:
//  q0: h0..7   = hvLO(n,0),hvHI(n,0),hvLO(n,1),hvHI(n,1)
//  q1: h8..15  = hvLO(n,2),hvHI(n,2),hvLO(n,3),hvHI(n,3)
//  q2: h16..19 = pack(hl(n,0),hl(n,1)), pack(hl(n,2),hl(n,3)), [x0 wt], [x0 wt]
//  q3: all x0-weight garbage (Fb rows k>=20 are zero)
#define MSTEP_REG(BA, PUB) {                                                                \
  i32x2 _lo = __builtin_bit_cast(i32x2, hvS);                                               \
  int _hlu = (int)(unsigned)__builtin_bit_cast(unsigned short, hlS);                        \
  int _b0 = __builtin_amdgcn_ds_bpermute(adrA, _lo.x);                                      \
  int _b1 = __builtin_amdgcn_ds_bpermute(adrA, _lo.y);                                      \
  int _b2 = __builtin_amdgcn_ds_bpermute(adrB, _lo.x);                                      \
  int _b3 = __builtin_amdgcn_ds_bpermute(adrB, _lo.y);                                      \
  int _hA = __builtin_amdgcn_ds_bpermute(adr0, _hlu);                                       \
  int _hB = __builtin_amdgcn_ds_bpermute(adr1, _hlu);                                       \
  int _hC = __builtin_amdgcn_ds_bpermute(adr2, _hlu);                                       \
  int _hD = __builtin_amdgcn_ds_bpermute(adr3, _hlu);                                       \
  int _w0 = (q < 2) ? _b0 : ((_hA & 0xffff) | (_hB << 16));                                 \
  int _w1 = (q < 2) ? _b1 : ((_hC & 0xffff) | (_hD << 16));                                 \
  i32x4 _bbi = { _w0, _w1, _b2, _b3 };                                                      \
  f16x8 bb = __builtin_bit_cast(f16x8, _bbi);                                               \
  f32x4 di = MFMA(Fb0, bb, MFMA(Fa0, (BA), Bi));                                            \
  f32x4 df = MFMA(Fb1, bb, MFMA(Fa1, (BA), Bf));                                            \
  f32x4 dg = MFMA(Fb2, bb, MFMA(Fa2, (BA), Bg));                                            \
  f32x4 dn = MFMA(Fb3, bb, MFMA(Fa3, (BA), Bo));                                            \
  f32x4 dl = MFMA(Fb4, bb, MFMA(Fa4, (BA), BL));                                            \
  f16x4 hv; f16 hl; CELLS5(di, df, dg, dn, dl, hv, hl)                                      \
  hvS = hv; hlS = hl;                                                                       \
  f16* dp_ = (PUB);                                                                         \
  if (dp_) { *(f16x4*)&dp_[n * 64 + SWZ1(n, q * 4)] = hv;                                   \
             dp_[n * 64 + SWZ1(n, 16 + q)] = hl; } }

// L0 substep (unchanged LDS ring): read slot S [x 8|h0 20|pad4], write h0 into
// slot D (c8..27), publish into PUB (c0..19).
#define L0S(S, D, PUB) {                                                                    \
  f16x8 b0 = *(const f16x8*)&zT0[S][n * 64 + SWZ1(n, q * 8)];                               \
  f32x4 di = MFMA(Fa0, b0, Bi), df = MFMA(Fa1, b0, Bf), dg = MFMA(Fa2, b0, Bg),             \
        dn = MFMA(Fa3, b0, Bo), dl = MFMA(Fa4, b0, BL);                                     \
  f16x4 hv; f16 hl; CELLS5(di, df, dg, dn, dl, hv, hl)                                      \
  *(f16x4*)&zT0[D][n * 64 + SWZ1(n, 8 + q * 4)] = hv;                                       \
  zT0[D][n * 64 + SWZ1(n, 24 + q)] = hl;                                                    \
  f16* dp_ = (PUB);                                                                         \
  *(f16x4*)&dp_[n * 64 + SWZ1(n, q * 4)] = hv;                                              \
  dp_[n * 64 + SWZ1(n, 16 + q)] = hl; }

__global__ __launch_bounds__(192, 2) void lstm3_ws_kernel(
    const float* __restrict__ x,
    const float* __restrict__ Wih0, const float* __restrict__ Whh0,
    const float* __restrict__ bih0, const float* __restrict__ bhh0,
    const float* __restrict__ Wih1, const float* __restrict__ Whh1,
    const float* __restrict__ bih1, const float* __restrict__ bhh1,
    const float* __restrict__ Wih2, const float* __restrict__ Whh2,
    const float* __restrict__ bih2, const float* __restrict__ bhh2,
    const float* __restrict__ fc1w, const float* __restrict__ fc1b,
    const float* __restrict__ fc2w, const float* __restrict__ fc2b,
    float* __restrict__ out)
{
  __shared__ __align__(16) f16 zT0[4][16 * 64];     // slot s: [x(t) 8|h0(t-1) 20|pad]
  __shared__ __align__(16) f16 zT1[2][4][16 * 64];  // parity,sub: [h0 20|pad44]
  __shared__ __align__(16) f16 zT2[2][4][16 * 64];  // parity,sub: [h1 20|pad12|h2fin 20|pad]
  __shared__ __align__(16) float pbuf[64];          // fc2 partials

  const int tid  = threadIdx.x;
  const int w    = tid >> 6;        // wave id = layer id
  const int lane = tid & 63;
  const int n = lane & 15;          // batch elem (N index)
  const int q = lane >> 4;          // quad

  // bpermute source-lane byte addresses (lane*4)
  const int adrA = 4 * (n + 32 * (q & 1));
  const int adrB = 4 * (n + 16 + 32 * (q & 1));
  const int adr0 = 4 * n, adr1 = 4 * (n + 16), adr2 = 4 * (n + 32), adr3 = 4 * (n + 48);

  // ---- zero z buffers (h(.)=0, c implicit 0, pads 0) ----
  {
    f16x8 zer;
#pragma unroll
    for (int j = 0; j < 8; ++j) zer[j] = (f16)0.f;
    for (int i = tid; i < 512; i += 192)  ((f16x8*)&zT0[0][0])[i] = zer;
    for (int i = tid; i < 1024; i += 192) ((f16x8*)&zT1[0][0][0])[i] = zer;
    for (int i = tid; i < 1024; i += 192) ((f16x8*)&zT2[0][0][0])[i] = zer;
  }
  __syncthreads();

  // ---- per-wave register-resident fragments (PRESCALED) ----
  // tiles 0..3: gate T, units 0..15. tile 4: unit-major leftover:
  // row = (m&3)*20 + 16 + (m>>2)  -> lane(q,n) reg r = gate r, unit 16+q.
  auto rowmap = [](int T, int m) { return T < 4 ? T * 20 + m : (m & 3) * 20 + 16 + (m >> 2); };
  auto gscale = [](int T, int m) {
    int g = (T < 4) ? T : (m & 3);
    return (g == 2) ? -KS2 : -KS1;
  };

  f16x8 Fa0{}, Fa1{}, Fa2{}, Fa3{}, Fa4{};   // k-chunk 0 (w0: full [x|h] K)
  f16x8 Fb0{}, Fb1{}, Fb2{}, Fb3{}, Fb4{};   // k-chunk 1 (h_self; unused w0)
  f32x4 Bi{}, Bf{}, Bg{}, Bo{}, BL{};
  float c0 = 0.f, c1 = 0.f, c2 = 0.f, c3 = 0.f, cL = 0.f;
  f16x4 hvS{};                     // register h_self state (w1/w2)
  f16 hlS = (f16)0.f;

  if (w == 0) {
    auto gA0 = [&](int T) {
      int row = rowmap(T, n);
      float sc = gscale(T, n);
      f16x8 r;
#pragma unroll
      for (int j = 0; j < 8; ++j) {
        int k = q * 8 + j;
        float v = (k < 8) ? Wih0[row * 8 + k] : (k < 28 ? Whh0[row * 20 + k - 8] : 0.f);
        r[j] = (f16)(sc * v);
      }
      return r;
    };
    Fa0 = gA0(0); Fa1 = gA0(1); Fa2 = gA0(2); Fa3 = gA0(3); Fa4 = gA0(4);
    auto gB = [&](int T) {
      f32x4 r;
#pragma unroll
      for (int j = 0; j < 4; ++j) {
        int m = q * 4 + j;
        int row = rowmap(T, m);
        r[j] = gscale(T, m) * (bih0[row] + bhh0[row]);
      }
      return r;
    };
    Bi = gB(0); Bf = gB(1); Bg = gB(2); Bo = gB(3); BL = gB(4);
  } else {
    const float* Wi = (w == 1) ? Wih1 : Wih2;
    const float* Wh = (w == 1) ? Whh1 : Whh2;
    const float* bi = (w == 1) ? bih1 : bih2;
    const float* bh = (w == 1) ? bhh1 : bhh2;
    // chunk 0 covers k=0..31 = [h_in 20 | 0 pad]; chunk 1 = [h_self 20 | 0]
    auto gA = [&](int T, int c) {
      int row = rowmap(T, n);
      float sc = gscale(T, n);
      const float* W = c ? Wh : Wi;
      f16x8 r;
#pragma unroll
      for (int j = 0; j < 8; ++j) {
        int k = q * 8 + j;
        r[j] = (f16)((k < 20) ? sc * W[row * 20 + k] : 0.f);
      }
      return r;
    };
    Fa0 = gA(0, 0); Fb0 = gA(0, 1);
    Fa1 = gA(1, 0); Fb1 = gA(1, 1);
    Fa2 = gA(2, 0); Fb2 = gA(2, 1);
    Fa3 = gA(3, 0); Fb3 = gA(3, 1);
    Fa4 = gA(4, 0); Fb4 = gA(4, 1);
    auto gB = [&](int T) {
      f32x4 r;
#pragma unroll
      for (int j = 0; j < 4; ++j) {
        int m = q * 4 + j;
        int row = rowmap(T, m);
        r[j] = gscale(T, m) * (bi[row] + bh[row]);
      }
      return r;
    };
    Bi = gB(0); Bf = gB(1); Bg = gB(2); Bo = gB(3); BL = gB(4);
  }

  // x prefetch (wave0): dwordx4 = pair block of 2 timesteps.
  // pair p floats 16p..16p+15: q0,q1 -> t=2p f0..7; q2,q3 -> t=2p+1 f0..7.
  // group j = pairs 2j, 2j+1 (timesteps 4j..4j+3).
  const float* xb = x + (size_t)(blockIdx.x * 16 + n) * (T_LEN * 8) + 4 * q;
  f32x4 xA{}, xB{};
  if (w == 0) {
    xA = *(const f32x4*)(xb);        // pair 0
    xB = *(const f32x4*)(xb + 16);   // pair 1
  }

  // ---- main loop: 4 timesteps per barrier ----
#pragma unroll 1
  for (int j = 0; j <= NJ; ++j) {
    asm volatile("" ::: "memory");   // pin LDS traffic in-loop (R4 fix)
    __builtin_amdgcn_s_setprio(1);   // computing waves outrank barrier-parked
    const int wp = j & 1, rp = wp ^ 1;
    if (w == 0) {
      if (j <= 83) {
        // stage x group j: pair 2j -> slots 0/1, pair 2j+1 -> slots 2/3
        f16x4 xh;
        xh[0] = (f16)xA[0]; xh[1] = (f16)xA[1]; xh[2] = (f16)xA[2]; xh[3] = (f16)xA[3];
        *(f16x4*)&zT0[q >> 1][n * 64 + SWZ1(n, 4 * (q & 1))] = xh;
        xh[0] = (f16)xB[0]; xh[1] = (f16)xB[1]; xh[2] = (f16)xB[2]; xh[3] = (f16)xB[3];
        *(f16x4*)&zT0[2 + (q >> 1)][n * 64 + SWZ1(n, 4 * (q & 1))] = xh;
        // prefetch group j+1 (slack: one full iteration >> HBM latency)
        int g = (j + 1 > 83) ? 83 : j + 1;
        xA = *(const f32x4*)(xb + (size_t)(2 * g) * 16);
        xB = *(const f32x4*)(xb + (size_t)(2 * g + 1) * 16);
        f16* p1 = &zT1[wp][0][0];
        L0S(0, 1, p1 + 0 * 1024)   // t=4j
        L0S(1, 2, p1 + 1 * 1024)   // t=4j+1
        L0S(2, 3, p1 + 2 * 1024)   // t=4j+2
        L0S(3, 0, p1 + 3 * 1024)   // t=4j+3 (h0 -> slot0 for next iter)
      }
    } else if (w == 1) {
      if (j >= 1 && j <= 84) {
        // L1 group j-1: h_in = h0 (published last iter), h_self in registers
        f16* s1 = &zT1[rp][0][0];
        f16x8 ba0 = *(const f16x8*)&s1[0 * 1024 + n * 64 + SWZ1(n, q * 8)];
        f16x8 ba1 = *(const f16x8*)&s1[1 * 1024 + n * 64 + SWZ1(n, q * 8)];
        f16x8 ba2 = *(const f16x8*)&s1[2 * 1024 + n * 64 + SWZ1(n, q * 8)];
        f16x8 ba3 = *(const f16x8*)&s1[3 * 1024 + n * 64 + SWZ1(n, q * 8)];
        f16* p2 = &zT2[wp][0][0];
        MSTEP_REG(ba0, p2 + 0 * 1024)
        MSTEP_REG(ba1, p2 + 1 * 1024)
        MSTEP_REG(ba2, p2 + 2 * 1024)
        MSTEP_REG(ba3, p2 + 3 * 1024)
      }
    } else {
      if (j >= 2) {
        // L2 group j-2: h_in = h1, h_self in registers; no publishes
        f16* s2 = &zT2[rp][0][0];
        f16x8 ca0 = *(const f16x8*)&s2[0 * 1024 + n * 64 + SWZ1(n, q * 8)];
        f16x8 ca1 = *(const f16x8*)&s2[1 * 1024 + n * 64 + SWZ1(n, q * 8)];
        f16x8 ca2 = *(const f16x8*)&s2[2 * 1024 + n * 64 + SWZ1(n, q * 8)];
        f16x8 ca3 = *(const f16x8*)&s2[3 * 1024 + n * 64 + SWZ1(n, q * 8)];
        MSTEP_REG(ca0, (f16*)nullptr)
        MSTEP_REG(ca1, (f16*)nullptr)
        MSTEP_REG(ca2, (f16*)nullptr)
        MSTEP_REG(ca3, (f16*)nullptr)
      }
    }
    __builtin_amdgcn_s_setprio(0);
    // LDS-only barrier: cross-wave handoff needs lgkmcnt(0), NOT vmcnt(0) —
    // wave0's in-flight x loads stay outstanding across it (R9 fix).
    asm volatile("s_waitcnt lgkmcnt(0)\n\ts_barrier" ::: "memory");
  }

  // ---- FC head (wave2): final h2(335) lives in hvS/hlS registers.
  if (w == 2) {
    // park h2 in LDS (c32..51 of zT2[1][0]) so each lane can read all 20 units
    *(f16x4*)&zT2[1][0][n * 64 + SWZ1(n, 32 + q * 4)] = hvS;
    zT2[1][0][n * 64 + SWZ1(n, 48 + q)] = hlS;
    asm volatile("s_waitcnt lgkmcnt(0)" ::: "memory");
    const f16* hb = &zT2[1][0][0];
    f16x4 hv0 = *(const f16x4*)&hb[n * 64 + SWZ1(n, 32)];
    f16x4 hv1 = *(const f16x4*)&hb[n * 64 + SWZ1(n, 36)];
    f16x4 hv2 = *(const f16x4*)&hb[n * 64 + SWZ1(n, 40)];
    f16x4 hv3 = *(const f16x4*)&hb[n * 64 + SWZ1(n, 44)];
    f16x4 hv4 = *(const f16x4*)&hb[n * 64 + SWZ1(n, 48)];
    float p = 0.f;
#pragma unroll
    for (int i = 0; i < 5; ++i) {
      int d = q * 5 + i;
      const float* wr = fc1w + d * 20;
      float s = fc1b[d]
        + wr[0]  * (float)hv0[0] + wr[1]  * (float)hv0[1] + wr[2]  * (float)hv0[2] + wr[3]  * (float)hv0[3]
        + wr[4]  * (float)hv1[0] + wr[5]  * (float)hv1[1] + wr[6]  * (float)hv1[2] + wr[7]  * (float)hv1[3]
        + wr[8]  * (float)hv2[0] + wr[9]  * (float)hv2[1] + wr[10] * (float)hv2[2] + wr[11] * (float)hv2[3]
        + wr[12] * (float)hv3[0] + wr[13] * (float)hv3[1] + wr[14] * (float)hv3[2] + wr[15] * (float)hv3[3]
        + wr[16] * (float)hv4[0] + wr[17] * (float)hv4[1] + wr[18] * (float)hv4[2] + wr[19] * (float)hv4[3];
      p += fc2w[d] * fmaxf(s, 0.f);
    }
    pbuf[n * 4 + q] = p;            // wave-internal, in-order
    if (q == 0) {
      f32x4 pv = *(const f32x4*)&pbuf[n * 4];
      out[blockIdx.x * 16 + n] = pv[0] + pv[1] + pv[2] + pv[3] + fc2b[0];
    }
  }
}

extern "C" void kernel_launch(void* const* d_in, const int* in_sizes, int n_in,
                              void* d_out, int out_size, void* d_ws, size_t ws_size,
                              hipStream_t stream) {
  const float* x    = (const float*)d_in[0];
  const float* Wih0 = (const float*)d_in[1];
  const float* Whh0 = (const float*)d_in[2];
  const float* bih0 = (const float*)d_in[3];
  const float* bhh0 = (const float*)d_in[4];
  const float* Wih1 = (const float*)d_in[5];
  const float* Whh1 = (const float*)d_in[6];
  const float* bih1 = (const float*)d_in[7];
  const float* bhh1 = (const float*)d_in[8];
  const float* Wih2 = (const float*)d_in[9];
  const float* Whh2 = (const float*)d_in[10];
  const float* bih2 = (const float*)d_in[11];
  const float* bhh2 = (const float*)d_in[12];
  const float* fc1w = (const float*)d_in[13];
  const float* fc1b = (const float*)d_in[14];
  const float* fc2w = (const float*)d_in[15];
  const float* fc2b = (const float*)d_in[16];
  float* out = (float*)d_out;

  hipLaunchKernelGGL(lstm3_ws_kernel, dim3(8192 / 16), dim3(192), 0, stream,
                     x, Wih0, Whh0, bih0, bhh0,
                     Wih1, Whh1, bih1, bhh1,
                     Wih2, Whh2, bih2, bhh2,
                     fc1w, fc1b, fc2w, fc2b, out);
}